// Round 1
// baseline (1192.339 us; speedup 1.0000x reference)
//
#include <hip/hip_runtime.h>
#include <math.h>

#define H 256
#define BATCH 128
#define CDIM 10
#define HH (H*H)      // 65536
#define NCHEB 16      // Chebyshev degree

// ---------------- prep: t = (X - c I)/h ; cur = a[N-1] I + 2 a[N] t ; prev = a[N] I
__global__ void prep_kernel(const float4* __restrict__ X4, float4* __restrict__ t4,
                            float4* __restrict__ cur4, float4* __restrict__ prev4,
                            float cc, float hinv, float aN, float aNm1)
{
    const int total4 = BATCH * HH / 4;
    for (int idx = blockIdx.x * blockDim.x + threadIdx.x; idx < total4;
         idx += gridDim.x * blockDim.x) {
        int ij4 = idx & (HH/4 - 1);
        int i = ij4 >> 6;             // row
        int jb = (ij4 & 63) << 2;     // first col of the 4
        float4 x = X4[idx];
        float d0 = (i == jb+0) ? 1.0f : 0.0f;
        float d1 = (i == jb+1) ? 1.0f : 0.0f;
        float d2 = (i == jb+2) ? 1.0f : 0.0f;
        float d3 = (i == jb+3) ? 1.0f : 0.0f;
        float4 tv;
        tv.x = (x.x - cc*d0) * hinv;
        tv.y = (x.y - cc*d1) * hinv;
        tv.z = (x.z - cc*d2) * hinv;
        tv.w = (x.w - cc*d3) * hinv;
        t4[idx] = tv;
        float4 cu;
        cu.x = aNm1*d0 + 2.0f*aN*tv.x;
        cu.y = aNm1*d1 + 2.0f*aN*tv.y;
        cu.z = aNm1*d2 + 2.0f*aN*tv.z;
        cu.w = aNm1*d3 + 2.0f*aN*tv.w;
        cur4[idx] = cu;
        float4 pv;
        pv.x = aN*d0; pv.y = aN*d1; pv.z = aN*d2; pv.w = aN*d3;
        prev4[idx] = pv;
    }
}

// ---------------- batched matmul: Out = s*(A@B) - Prev + adiag*I  (in-place over Prev OK)
#define TILE 128
#define BK 16

__global__ __launch_bounds__(256)
void mm_kernel(const float* __restrict__ A, const float* __restrict__ B,
               const float* __restrict__ Prev, float* __restrict__ Out,
               long sA, long sB, long sO, float s, float adiag, int hasPrev)
{
    __shared__ float As[BK][TILE];   // As[k][i]  (A transposed in LDS)
    __shared__ float Bs[BK][TILE];   // Bs[k][j]

    const int bz = blockIdx.z;
    const float* Ab = A + (long)bz * sA;
    const float* Bb = B + (long)bz * sB;
    float* Ob       = Out + (long)bz * sO;
    const float* Pb = Prev + (long)bz * sO;

    const int i0 = blockIdx.x * TILE;
    const int j0 = blockIdx.y * TILE;
    const int tid = threadIdx.x;
    const int tr = tid >> 4;    // 0..15 row group
    const int tc = tid & 15;    // 0..15 col group

    float acc[8][8] = {};

    for (int k0 = 0; k0 < H; k0 += BK) {
        // A tile: rows i0..i0+127, cols k0..k0+15 -> As[k][i]
        {
            int r = tid >> 2;      // 0..63
            int q = tid & 3;       // 0..3 (k quad)
            #pragma unroll
            for (int hh2 = 0; hh2 < 2; hh2++) {
                int row = r + hh2 * 64;
                float4 v = *reinterpret_cast<const float4*>(&Ab[(long)(i0 + row) * H + k0 + q*4]);
                As[q*4+0][row] = v.x;
                As[q*4+1][row] = v.y;
                As[q*4+2][row] = v.z;
                As[q*4+3][row] = v.w;
            }
        }
        // B tile: rows k0..k0+15, cols j0..j0+127 -> Bs[k][j]
        {
            int kk = tid >> 5;     // 0..7
            int cq = tid & 31;     // 0..31
            #pragma unroll
            for (int hh2 = 0; hh2 < 2; hh2++) {
                int krow = kk + hh2 * 8;
                float4 v = *reinterpret_cast<const float4*>(&Bb[(long)(k0 + krow) * H + j0 + cq*4]);
                *reinterpret_cast<float4*>(&Bs[krow][cq*4]) = v;
            }
        }
        __syncthreads();

        #pragma unroll
        for (int k = 0; k < BK; k++) {
            float a[8], b[8];
            *reinterpret_cast<float4*>(&a[0]) = *reinterpret_cast<const float4*>(&As[k][tr*8]);
            *reinterpret_cast<float4*>(&a[4]) = *reinterpret_cast<const float4*>(&As[k][tr*8+4]);
            *reinterpret_cast<float4*>(&b[0]) = *reinterpret_cast<const float4*>(&Bs[k][tc*8]);
            *reinterpret_cast<float4*>(&b[4]) = *reinterpret_cast<const float4*>(&Bs[k][tc*8+4]);
            #pragma unroll
            for (int ii = 0; ii < 8; ii++)
                #pragma unroll
                for (int jj = 0; jj < 8; jj++)
                    acc[ii][jj] = fmaf(a[ii], b[jj], acc[ii][jj]);
        }
        __syncthreads();
    }

    // epilogue
    #pragma unroll
    for (int ii = 0; ii < 8; ii++) {
        int i = i0 + tr*8 + ii;
        long base = (long)i * H + j0 + tc*8;
        float v[8];
        #pragma unroll
        for (int jj = 0; jj < 8; jj++) v[jj] = s * acc[ii][jj];
        if (hasPrev) {
            float4 p0 = *reinterpret_cast<const float4*>(&Pb[base]);
            float4 p1 = *reinterpret_cast<const float4*>(&Pb[base+4]);
            v[0]-=p0.x; v[1]-=p0.y; v[2]-=p0.z; v[3]-=p0.w;
            v[4]-=p1.x; v[5]-=p1.y; v[6]-=p1.z; v[7]-=p1.w;
        }
        int jd = i - (j0 + tc*8);
        if (jd >= 0 && jd < 8) v[jd] += adiag;
        float4 o0 = make_float4(v[0], v[1], v[2], v[3]);
        float4 o1 = make_float4(v[4], v[5], v[6], v[7]);
        *reinterpret_cast<float4*>(&Ob[base])   = o0;
        *reinterpret_cast<float4*>(&Ob[base+4]) = o1;
    }
}

// ---------------- Wsym = 0.5 (W + W^T)
__global__ void symw_kernel(const float* __restrict__ W, float* __restrict__ Ws)
{
    const int total = CDIM * HH;
    for (int idx = blockIdx.x * blockDim.x + threadIdx.x; idx < total;
         idx += gridDim.x * blockDim.x) {
        int c  = idx >> 16;
        int ij = idx & (HH-1);
        int i = ij >> 8, j = ij & (H-1);
        Ws[idx] = 0.5f * (W[idx] + W[(c << 16) + (j << 8) + i]);
    }
}

// ---------------- output[b,c] = sum_ij Wsym[c,ij] * feats[b,ij]
__global__ __launch_bounds__(256)
void out_kernel(const float* __restrict__ feats, const float* __restrict__ Ws,
                float* __restrict__ out)
{
    int b = blockIdx.x;
    const float* fb = feats + (long)b * HH;
    float acc[CDIM] = {};
    for (int idx = threadIdx.x; idx < HH; idx += 256) {
        float f = fb[idx];
        #pragma unroll
        for (int c = 0; c < CDIM; c++)
            acc[c] = fmaf(Ws[c*HH + idx], f, acc[c]);
    }
    __shared__ float red[4][CDIM];
    int lane = threadIdx.x & 63;
    int wv = threadIdx.x >> 6;
    #pragma unroll
    for (int c = 0; c < CDIM; c++) {
        float v = acc[c];
        #pragma unroll
        for (int off = 32; off >= 1; off >>= 1) v += __shfl_down(v, off, 64);
        if (lane == 0) red[wv][c] = v;
    }
    __syncthreads();
    if (threadIdx.x < CDIM) {
        float v = red[0][threadIdx.x] + red[1][threadIdx.x]
                + red[2][threadIdx.x] + red[3][threadIdx.x];
        out[b*CDIM + threadIdx.x] = v;
    }
}

// ---------------- center = mean_b feats
__global__ void center_kernel(const float* __restrict__ feats, float* __restrict__ center)
{
    int idx = blockIdx.x * blockDim.x + threadIdx.x;
    if (idx < HH) {
        float s = 0.0f;
        for (int b = 0; b < BATCH; b++) s += feats[(long)b * HH + idx];
        center[idx] = s * (1.0f / BATCH);
    }
}

// ---------------- g[c] = sum_ij P[c,i,j] P[c,j,i]
__global__ __launch_bounds__(256)
void g_kernel(const float* __restrict__ P, float* __restrict__ gpart)
{
    int c = blockIdx.x;
    const float* Pc = P + (long)c * HH;
    float acc = 0.0f;
    for (int idx = threadIdx.x; idx < HH; idx += 256) {
        int i = idx >> 8, j = idx & (H-1);
        acc += Pc[idx] * Pc[(j << 8) + i];
    }
    __shared__ float red[4];
    int lane = threadIdx.x & 63;
    int wv = threadIdx.x >> 6;
    #pragma unroll
    for (int off = 32; off >= 1; off >>= 1) acc += __shfl_down(acc, off, 64);
    if (lane == 0) red[wv] = acc;
    __syncthreads();
    if (threadIdx.x == 0)
        gpart[c] = red[0] + red[1] + red[2] + red[3];
}

__global__ void gmean_kernel(const float* __restrict__ gpart, float* __restrict__ out)
{
    if (threadIdx.x == 0) {
        float s = 0.0f;
        for (int c = 0; c < CDIM; c++) s += gpart[c];
        out[BATCH*CDIM] = s * (1.0f / CDIM);
    }
}

extern "C" void kernel_launch(void* const* d_in, const int* in_sizes, int n_in,
                              void* d_out, int out_size, void* d_ws, size_t ws_size,
                              hipStream_t stream)
{
    const float* X = (const float*)d_in[0];   // [128,256,256]
    const float* W = (const float*)d_in[1];   // [10,256,256]
    float* out = (float*)d_out;               // 1281 floats

    float* t      = (float*)d_ws;
    float* bufA   = t    + (size_t)BATCH * HH;
    float* bufB   = bufA + (size_t)BATCH * HH;
    float* Wsym   = bufB + (size_t)BATCH * HH;
    float* center = Wsym + (size_t)CDIM * HH;
    float* P      = center + HH;
    float* gpart  = P + (size_t)CDIM * HH;

    // Chebyshev coefficients of log(x) on [lo, hi]  (closed form, host doubles)
    const double lo = 0.98, hi = 5.80;
    const double cc = 0.5 * (hi + lo), hh = 0.5 * (hi - lo);
    const double alpha = hh / cc;
    const double beta = (sqrt(1.0 - alpha*alpha) - 1.0) / alpha;
    double a[NCHEB + 1];
    a[0] = log(cc) - log(1.0 + beta*beta);
    double bp = 1.0;
    for (int k = 1; k <= NCHEB; k++) { bp *= beta; a[k] = -2.0 * bp / k; }

    prep_kernel<<<2048, 256, 0, stream>>>(
        (const float4*)X, (float4*)t, (float4*)bufA, (float4*)bufB,
        (float)cc, (float)(1.0 / hh), (float)a[NCHEB], (float)a[NCHEB-1]);

    // Clenshaw: b_k = a_k I + 2 t b_{k+1} - b_{k+2}
    float* cur = bufA;   // b_{N-1}
    float* prev = bufB;  // b_N
    dim3 mmgrid(2, 2, BATCH);
    for (int k = NCHEB - 2; k >= 1; k--) {
        mm_kernel<<<mmgrid, 256, 0, stream>>>(t, cur, prev, prev,
                                              HH, HH, HH, 2.0f, (float)a[k], 1);
        float* tmp = cur; cur = prev; prev = tmp;
    }
    // final: feats = a0 I + t b1 - b2
    mm_kernel<<<mmgrid, 256, 0, stream>>>(t, cur, prev, prev,
                                          HH, HH, HH, 1.0f, (float)a[0], 1);
    float* feats = prev;

    symw_kernel<<<64, 256, 0, stream>>>(W, Wsym);
    out_kernel<<<BATCH, 256, 0, stream>>>(feats, Wsym, out);
    center_kernel<<<HH/256, 256, 0, stream>>>(feats, center);

    dim3 pgrid(2, 2, CDIM);
    mm_kernel<<<pgrid, 256, 0, stream>>>(Wsym, center, P, P,
                                         HH, 0, HH, 1.0f, 0.0f, 0);
    g_kernel<<<CDIM, 256, 0, stream>>>(P, gpart);
    gmean_kernel<<<1, 64, 0, stream>>>(gpart, out);
}

// Round 2
// 359.586 us; speedup vs baseline: 3.3159x; 3.3159x over previous
//
#include <hip/hip_runtime.h>
#include <math.h>

#define H 256
#define BATCH 128
#define CDIM 10
#define HH (H*H)      // 65536
#define NCHEB 12      // Chebyshev degree (tail ~3e-6, far below bf16 noise)

typedef unsigned short u16;
typedef unsigned int u32;
typedef __attribute__((ext_vector_type(8))) short bf16x8;
typedef __attribute__((ext_vector_type(4))) float f32x4;

__device__ __forceinline__ u16 f2bf(float f){
    u32 u = __float_as_uint(f);
    u = (u + 0x7FFFu + ((u >> 16) & 1u)) >> 16;   // RNE
    return (u16)u;
}
__device__ __forceinline__ float bf2f(u16 h){
    return __uint_as_float(((u32)h) << 16);
}

// ---------------- prep: t = (X - c I)/h (bf16); cur = a11 I + 2 a12 t; prev = a12 I
__global__ void prep_kernel(const float4* __restrict__ X4, ushort4* __restrict__ t4,
                            ushort4* __restrict__ cur4, ushort4* __restrict__ prev4,
                            float cc, float hinv, float aN, float aNm1)
{
    const int total4 = BATCH * HH / 4;
    for (int idx = blockIdx.x * blockDim.x + threadIdx.x; idx < total4;
         idx += gridDim.x * blockDim.x) {
        int ij4 = idx & (HH/4 - 1);
        int i = ij4 >> 6;
        int jb = (ij4 & 63) << 2;
        float4 x = X4[idx];
        float d0 = (i == jb+0) ? 1.0f : 0.0f;
        float d1 = (i == jb+1) ? 1.0f : 0.0f;
        float d2 = (i == jb+2) ? 1.0f : 0.0f;
        float d3 = (i == jb+3) ? 1.0f : 0.0f;
        float t0 = (x.x - cc*d0) * hinv;
        float t1 = (x.y - cc*d1) * hinv;
        float t2 = (x.z - cc*d2) * hinv;
        float t3 = (x.w - cc*d3) * hinv;
        ushort4 to, co, po;
        to.x = f2bf(t0); to.y = f2bf(t1); to.z = f2bf(t2); to.w = f2bf(t3);
        co.x = f2bf(aNm1*d0 + 2.0f*aN*t0);
        co.y = f2bf(aNm1*d1 + 2.0f*aN*t1);
        co.z = f2bf(aNm1*d2 + 2.0f*aN*t2);
        co.w = f2bf(aNm1*d3 + 2.0f*aN*t3);
        po.x = f2bf(aN*d0); po.y = f2bf(aN*d1); po.z = f2bf(aN*d2); po.w = f2bf(aN*d3);
        t4[idx] = to; cur4[idx] = co; prev4[idx] = po;
    }
}

// ---------------- bf16 MFMA batched mm: Out = sc*(A@B) - Prev + adiag*I
// All of A, B, Prev are SYMMETRIC 256x256 bf16 (so B-fragments load like A-fragments).
// FINAL=1 writes fp32, else bf16 (in-place over Prev is safe: element-wise RMW per thread).
template<int FINAL>
__global__ __launch_bounds__(256)
void mm_bf16_kernel(const u16* __restrict__ A, const u16* __restrict__ B,
                    const u16* __restrict__ Prev, void* __restrict__ Out,
                    float sc, float adiag)
{
    __shared__ u16 Als[128*64];   // [row][64 k] bf16, 16B slots XOR-swizzled by row&7
    __shared__ u16 Bls[128*64];

    const int bz = blockIdx.z;
    const u16* Ab = A + (size_t)bz * HH;
    const u16* Bb = B + (size_t)bz * HH;
    const u16* Pb = Prev + (size_t)bz * HH;

    const int i0 = blockIdx.x * 128, j0 = blockIdx.y * 128;
    const int tid = threadIdx.x;
    const int lane = tid & 63;
    const int w = tid >> 6, wr = w >> 1, wc = w & 1;

    // staging: thread covers tile-row (tid>>1), slots (tid&1)*4 .. +3 (16B each)
    const int st_row = tid >> 1;
    const int st_s0  = (tid & 1) * 4;
    const int st_x   = st_row & 7;

    f32x4 acc[4][4];
    #pragma unroll
    for (int m = 0; m < 4; m++)
        #pragma unroll
        for (int n = 0; n < 4; n++)
            acc[m][n] = (f32x4)(0.0f);

    for (int k0 = 0; k0 < H; k0 += 64) {
        #pragma unroll
        for (int i = 0; i < 4; i++) {
            int s = st_s0 + i;
            int gs = s ^ st_x;   // LDS[row][s] = global[row][s ^ (row&7)]
            uint4 va = *reinterpret_cast<const uint4*>(
                (const char*)Ab + ((size_t)(i0 + st_row) * H + k0) * 2 + gs * 16);
            *reinterpret_cast<uint4*>((char*)Als + st_row * 128 + s * 16) = va;
            uint4 vb = *reinterpret_cast<const uint4*>(
                (const char*)Bb + ((size_t)(j0 + st_row) * H + k0) * 2 + gs * 16);
            *reinterpret_cast<uint4*>((char*)Bls + st_row * 128 + s * 16) = vb;
        }
        __syncthreads();

        #pragma unroll
        for (int kk = 0; kk < 2; kk++) {
            bf16x8 av[4], bv[4];
            int gsl = kk * 4 + (lane >> 4);
            #pragma unroll
            for (int m = 0; m < 4; m++) {
                int row = wr * 64 + m * 16 + (lane & 15);
                av[m] = *reinterpret_cast<const bf16x8*>(
                    (const char*)Als + row * 128 + ((gsl ^ (row & 7)) * 16));
            }
            #pragma unroll
            for (int n = 0; n < 4; n++) {
                int row = wc * 64 + n * 16 + (lane & 15);  // col of B == row (symmetric)
                bv[n] = *reinterpret_cast<const bf16x8*>(
                    (const char*)Bls + row * 128 + ((gsl ^ (row & 7)) * 16));
            }
            #pragma unroll
            for (int m = 0; m < 4; m++)
                #pragma unroll
                for (int n = 0; n < 4; n++)
                    acc[m][n] = __builtin_amdgcn_mfma_f32_16x16x32_bf16(
                        av[m], bv[n], acc[m][n], 0, 0, 0);
        }
        __syncthreads();
    }

    // epilogue: C/D layout col=lane&15, row=(lane>>4)*4+reg (m89/m91 verified)
    const int rl = (lane >> 4) * 4, cl = lane & 15;
    #pragma unroll
    for (int m = 0; m < 4; m++) {
        #pragma unroll
        for (int n = 0; n < 4; n++) {
            int gcol = j0 + wc * 64 + n * 16 + cl;
            #pragma unroll
            for (int r = 0; r < 4; r++) {
                int grow = i0 + wr * 64 + m * 16 + rl + r;
                float v = sc * acc[m][n][r] - bf2f(Pb[(size_t)grow * H + gcol]);
                if (grow == gcol) v += adiag;
                if (FINAL)
                    ((float*)Out)[(size_t)bz * HH + (size_t)grow * H + gcol] = v;
                else
                    ((u16*)Out)[(size_t)bz * HH + (size_t)grow * H + gcol] = f2bf(v);
            }
        }
    }
}

// ---------------- fp32 matmul (for P = Wsym @ center only)
#define TILE 128
#define BK 16
__global__ __launch_bounds__(256)
void mm_kernel(const float* __restrict__ A, const float* __restrict__ B,
               float* __restrict__ Out, long sA, long sB, long sO)
{
    __shared__ float As[BK][TILE];
    __shared__ float Bs[BK][TILE];
    const int bz = blockIdx.z;
    const float* Ab = A + (long)bz * sA;
    const float* Bb = B + (long)bz * sB;
    float* Ob = Out + (long)bz * sO;
    const int i0 = blockIdx.x * TILE;
    const int j0 = blockIdx.y * TILE;
    const int tid = threadIdx.x;
    const int tr = tid >> 4, tc = tid & 15;
    float acc[8][8] = {};
    for (int k0 = 0; k0 < H; k0 += BK) {
        {
            int r = tid >> 2, q = tid & 3;
            #pragma unroll
            for (int h2 = 0; h2 < 2; h2++) {
                int row = r + h2 * 64;
                float4 v = *reinterpret_cast<const float4*>(&Ab[(long)(i0 + row) * H + k0 + q*4]);
                As[q*4+0][row] = v.x; As[q*4+1][row] = v.y;
                As[q*4+2][row] = v.z; As[q*4+3][row] = v.w;
            }
        }
        {
            int kk = tid >> 5, cq = tid & 31;
            #pragma unroll
            for (int h2 = 0; h2 < 2; h2++) {
                int krow = kk + h2 * 8;
                float4 v = *reinterpret_cast<const float4*>(&Bb[(long)(k0 + krow) * H + j0 + cq*4]);
                *reinterpret_cast<float4*>(&Bs[krow][cq*4]) = v;
            }
        }
        __syncthreads();
        #pragma unroll
        for (int k = 0; k < BK; k++) {
            float a[8], b[8];
            *reinterpret_cast<float4*>(&a[0]) = *reinterpret_cast<const float4*>(&As[k][tr*8]);
            *reinterpret_cast<float4*>(&a[4]) = *reinterpret_cast<const float4*>(&As[k][tr*8+4]);
            *reinterpret_cast<float4*>(&b[0]) = *reinterpret_cast<const float4*>(&Bs[k][tc*8]);
            *reinterpret_cast<float4*>(&b[4]) = *reinterpret_cast<const float4*>(&Bs[k][tc*8+4]);
            #pragma unroll
            for (int ii = 0; ii < 8; ii++)
                #pragma unroll
                for (int jj = 0; jj < 8; jj++)
                    acc[ii][jj] = fmaf(a[ii], b[jj], acc[ii][jj]);
        }
        __syncthreads();
    }
    #pragma unroll
    for (int ii = 0; ii < 8; ii++) {
        long base = (long)(i0 + tr*8 + ii) * H + j0 + tc*8;
        float4 o0 = make_float4(acc[ii][0], acc[ii][1], acc[ii][2], acc[ii][3]);
        float4 o1 = make_float4(acc[ii][4], acc[ii][5], acc[ii][6], acc[ii][7]);
        *reinterpret_cast<float4*>(&Ob[base])   = o0;
        *reinterpret_cast<float4*>(&Ob[base+4]) = o1;
    }
}

// ---------------- Wsym = 0.5 (W + W^T)
__global__ void symw_kernel(const float* __restrict__ W, float* __restrict__ Ws)
{
    const int total = CDIM * HH;
    for (int idx = blockIdx.x * blockDim.x + threadIdx.x; idx < total;
         idx += gridDim.x * blockDim.x) {
        int c  = idx >> 16;
        int ij = idx & (HH-1);
        int i = ij >> 8, j = ij & (H-1);
        Ws[idx] = 0.5f * (W[idx] + W[(c << 16) + (j << 8) + i]);
    }
}

// ---------------- out partials: grid (8 chunks, 128 b)
__global__ __launch_bounds__(256)
void out_partial_kernel(const float4* __restrict__ feats4, const float4* __restrict__ Ws4,
                        float* __restrict__ partial)
{
    const int ch = blockIdx.x, b = blockIdx.y;
    const int base = ch * 2048;
    const float4* fb = feats4 + (size_t)b * (HH/4) + base;
    float acc[CDIM];
    #pragma unroll
    for (int c = 0; c < CDIM; c++) acc[c] = 0.0f;
    #pragma unroll
    for (int i = 0; i < 8; i++) {
        int idx = threadIdx.x + i * 256;
        float4 f = fb[idx];
        #pragma unroll
        for (int c = 0; c < CDIM; c++) {
            float4 wv = Ws4[(size_t)c * (HH/4) + base + idx];
            acc[c] = fmaf(f.x, wv.x, fmaf(f.y, wv.y, fmaf(f.z, wv.z, fmaf(f.w, wv.w, acc[c]))));
        }
    }
    __shared__ float red[4][CDIM];
    int lane = threadIdx.x & 63, wv_ = threadIdx.x >> 6;
    #pragma unroll
    for (int c = 0; c < CDIM; c++) {
        float v = acc[c];
        #pragma unroll
        for (int off = 32; off >= 1; off >>= 1) v += __shfl_down(v, off, 64);
        if (lane == 0) red[wv_][c] = v;
    }
    __syncthreads();
    if (threadIdx.x < CDIM)
        partial[((size_t)b * 8 + ch) * CDIM + threadIdx.x] =
            red[0][threadIdx.x] + red[1][threadIdx.x] + red[2][threadIdx.x] + red[3][threadIdx.x];
}

__global__ void out_reduce_kernel(const float* __restrict__ partial, float* __restrict__ out)
{
    int idx = blockIdx.x * blockDim.x + threadIdx.x;
    if (idx < BATCH * CDIM) {
        int b = idx / CDIM, c = idx % CDIM;
        float v = 0.0f;
        #pragma unroll
        for (int ch = 0; ch < 8; ch++) v += partial[((size_t)b * 8 + ch) * CDIM + c];
        out[idx] = v;
    }
}

// ---------------- center = mean_b feats (float4 per thread)
__global__ void center_kernel(const float4* __restrict__ feats4, float4* __restrict__ center4)
{
    int idx = blockIdx.x * blockDim.x + threadIdx.x;  // 0..16383
    float4 sv = make_float4(0.f, 0.f, 0.f, 0.f);
    for (int b = 0; b < BATCH; b++) {
        float4 f = feats4[(size_t)b * (HH/4) + idx];
        sv.x += f.x; sv.y += f.y; sv.z += f.z; sv.w += f.w;
    }
    const float inv = 1.0f / BATCH;
    sv.x *= inv; sv.y *= inv; sv.z *= inv; sv.w *= inv;
    center4[idx] = sv;
}

// ---------------- g[c] = sum_ij P[c,i,j] P[c,j,i]
__global__ __launch_bounds__(256)
void g_kernel(const float* __restrict__ P, float* __restrict__ gpart)
{
    int c = blockIdx.x;
    const float* Pc = P + (size_t)c * HH;
    float acc = 0.0f;
    for (int idx = threadIdx.x; idx < HH; idx += 256) {
        int i = idx >> 8, j = idx & (H-1);
        acc += Pc[idx] * Pc[(j << 8) + i];
    }
    __shared__ float red[4];
    int lane = threadIdx.x & 63, wv = threadIdx.x >> 6;
    #pragma unroll
    for (int off = 32; off >= 1; off >>= 1) acc += __shfl_down(acc, off, 64);
    if (lane == 0) red[wv] = acc;
    __syncthreads();
    if (threadIdx.x == 0)
        gpart[c] = red[0] + red[1] + red[2] + red[3];
}

__global__ void gmean_kernel(const float* __restrict__ gpart, float* __restrict__ out)
{
    if (threadIdx.x == 0) {
        float s = 0.0f;
        for (int c = 0; c < CDIM; c++) s += gpart[c];
        out[BATCH*CDIM] = s * (1.0f / CDIM);
    }
}

extern "C" void kernel_launch(void* const* d_in, const int* in_sizes, int n_in,
                              void* d_out, int out_size, void* d_ws, size_t ws_size,
                              hipStream_t stream)
{
    const float* X = (const float*)d_in[0];   // [128,256,256]
    const float* W = (const float*)d_in[1];   // [10,256,256]
    float* out = (float*)d_out;               // 1281 floats

    char* wp = (char*)d_ws;
    u16* tb    = (u16*)wp;  wp += (size_t)BATCH * HH * 2;
    u16* curb  = (u16*)wp;  wp += (size_t)BATCH * HH * 2;
    u16* prevb = (u16*)wp;  wp += (size_t)BATCH * HH * 2;
    float* feats  = (float*)wp;  wp += (size_t)BATCH * HH * 4;
    float* Wsym   = (float*)wp;  wp += (size_t)CDIM * HH * 4;
    float* center = (float*)wp;  wp += (size_t)HH * 4;
    float* P      = (float*)wp;  wp += (size_t)CDIM * HH * 4;
    float* partial= (float*)wp;  wp += (size_t)BATCH * 8 * CDIM * 4;
    float* gpart  = (float*)wp;

    // Chebyshev coefficients of log(x) on [lo, hi] (closed form)
    const double lo = 0.98, hi = 5.80;
    const double cc = 0.5 * (hi + lo), hh = 0.5 * (hi - lo);
    const double alpha = hh / cc;
    const double beta = (sqrt(1.0 - alpha*alpha) - 1.0) / alpha;
    double a[NCHEB + 1];
    a[0] = log(cc) - log(1.0 + beta*beta);
    double bp = 1.0;
    for (int k = 1; k <= NCHEB; k++) { bp *= beta; a[k] = -2.0 * bp / k; }

    prep_kernel<<<2048, 256, 0, stream>>>(
        (const float4*)X, (ushort4*)tb, (ushort4*)curb, (ushort4*)prevb,
        (float)cc, (float)(1.0 / hh), (float)a[NCHEB], (float)a[NCHEB-1]);

    symw_kernel<<<64, 256, 0, stream>>>(W, Wsym);

    // Clenshaw: b_k = a_k I + 2 t b_{k+1} - b_{k+2}
    u16* cur = curb;
    u16* prev = prevb;
    dim3 mmgrid(2, 2, BATCH);
    for (int k = NCHEB - 2; k >= 1; k--) {
        mm_bf16_kernel<0><<<mmgrid, 256, 0, stream>>>(tb, cur, prev, prev, 2.0f, (float)a[k]);
        u16* tmp = cur; cur = prev; prev = tmp;
    }
    mm_bf16_kernel<1><<<mmgrid, 256, 0, stream>>>(tb, cur, prev, feats, 1.0f, (float)a[0]);

    out_partial_kernel<<<dim3(8, BATCH), 256, 0, stream>>>(
        (const float4*)feats, (const float4*)Wsym, partial);
    out_reduce_kernel<<<5, 256, 0, stream>>>(partial, out);

    center_kernel<<<64, 256, 0, stream>>>((const float4*)feats, (float4*)center);

    dim3 pgrid(2, 2, CDIM);
    mm_kernel<<<pgrid, 256, 0, stream>>>(Wsym, center, P, HH, 0, HH);
    g_kernel<<<CDIM, 256, 0, stream>>>(P, gpart);
    gmean_kernel<<<1, 64, 0, stream>>>(gpart, out);
}

// Round 3
// 166.312 us; speedup vs baseline: 7.1693x; 2.1621x over previous
//
#include <hip/hip_runtime.h>
#include <math.h>

#define H 256
#define BATCH 128
#define CDIM 10
#define HH (H*H)      // 65536
#define NCHEB 8       // PS-Chebyshev degree (tail ~1.5e-4, negligible vs bf16 noise)

typedef unsigned short u16;
typedef unsigned int u32;
typedef __attribute__((ext_vector_type(8))) short bf16x8;
typedef __attribute__((ext_vector_type(8))) unsigned short u16x8;
typedef __attribute__((ext_vector_type(4))) float f32x4;

__device__ __forceinline__ u16 f2bf(float f){
    u32 u = __float_as_uint(f);
    u = (u + 0x7FFFu + ((u >> 16) & 1u)) >> 16;   // RNE
    return (u16)u;
}
__device__ __forceinline__ float bf2f(u16 h){
    return __uint_as_float(((u32)h) << 16);
}

// ---------------- prep: t = (X - c I)/h  (bf16)
__global__ void prep_kernel(const float4* __restrict__ X4, ushort4* __restrict__ t4,
                            float cc, float hinv)
{
    const int total4 = BATCH * HH / 4;
    for (int idx = blockIdx.x * blockDim.x + threadIdx.x; idx < total4;
         idx += gridDim.x * blockDim.x) {
        int ij4 = idx & (HH/4 - 1);
        int i = ij4 >> 6;
        int jb = (ij4 & 63) << 2;
        float4 x = X4[idx];
        float d0 = (i == jb+0) ? 1.0f : 0.0f;
        float d1 = (i == jb+1) ? 1.0f : 0.0f;
        float d2 = (i == jb+2) ? 1.0f : 0.0f;
        float d3 = (i == jb+3) ? 1.0f : 0.0f;
        ushort4 to;
        to.x = f2bf((x.x - cc*d0) * hinv);
        to.y = f2bf((x.y - cc*d1) * hinv);
        to.z = f2bf((x.z - cc*d2) * hinv);
        to.w = f2bf((x.w - cc*d3) * hinv);
        t4[idx] = to;
    }
}

// ---------------- bf16 MFMA batched mm: Out = sc*(A@B) + ps*Prev + adiag*I
// A, B, Prev all SYMMETRIC 256x256 bf16 (B-fragments load like A-fragments).
// bstride: 0 -> B shared across batch, 1 -> per-batch. FINAL=1 -> fp32 out.
template<int FINAL, int HASPREV>
__global__ __launch_bounds__(256)
void mm_bf16_kernel(const u16* __restrict__ A, const u16* __restrict__ B,
                    const u16* __restrict__ Prev, void* __restrict__ Out,
                    int bstride, float sc, float ps, float adiag)
{
    __shared__ u16 Als[128*64];   // [row][64 k] bf16, 16B slots XOR-swizzled by row&7
    __shared__ u16 Bls[128*64];

    const int bz = blockIdx.z;
    const u16* Ab = A + (size_t)bz * HH;
    const u16* Bb = B + (size_t)bz * HH * bstride;
    const u16* Pb = HASPREV ? (Prev + (size_t)bz * HH) : A;  // dummy when unused

    const int i0 = blockIdx.x * 128, j0 = blockIdx.y * 128;
    const int tid = threadIdx.x;
    const int lane = tid & 63;
    const int w = tid >> 6, wr = w >> 1, wc = w & 1;

    const int st_row = tid >> 1;
    const int st_s0  = (tid & 1) * 4;
    const int st_x   = st_row & 7;

    f32x4 acc[4][4];
    #pragma unroll
    for (int m = 0; m < 4; m++)
        #pragma unroll
        for (int n = 0; n < 4; n++)
            acc[m][n] = (f32x4)(0.0f);

    for (int k0 = 0; k0 < H; k0 += 64) {
        #pragma unroll
        for (int i = 0; i < 4; i++) {
            int s = st_s0 + i;
            int gs = s ^ st_x;
            uint4 va = *reinterpret_cast<const uint4*>(
                (const char*)Ab + ((size_t)(i0 + st_row) * H + k0) * 2 + gs * 16);
            *reinterpret_cast<uint4*>((char*)Als + st_row * 128 + s * 16) = va;
            uint4 vb = *reinterpret_cast<const uint4*>(
                (const char*)Bb + ((size_t)(j0 + st_row) * H + k0) * 2 + gs * 16);
            *reinterpret_cast<uint4*>((char*)Bls + st_row * 128 + s * 16) = vb;
        }
        __syncthreads();

        #pragma unroll
        for (int kk = 0; kk < 2; kk++) {
            bf16x8 av[4], bv[4];
            int gsl = kk * 4 + (lane >> 4);
            #pragma unroll
            for (int m = 0; m < 4; m++) {
                int row = wr * 64 + m * 16 + (lane & 15);
                av[m] = *reinterpret_cast<const bf16x8*>(
                    (const char*)Als + row * 128 + ((gsl ^ (row & 7)) * 16));
            }
            #pragma unroll
            for (int n = 0; n < 4; n++) {
                int row = wc * 64 + n * 16 + (lane & 15);  // col of B == row (symmetric)
                bv[n] = *reinterpret_cast<const bf16x8*>(
                    (const char*)Bls + row * 128 + ((gsl ^ (row & 7)) * 16));
            }
            #pragma unroll
            for (int m = 0; m < 4; m++)
                #pragma unroll
                for (int n = 0; n < 4; n++)
                    acc[m][n] = __builtin_amdgcn_mfma_f32_16x16x32_bf16(
                        av[m], bv[n], acc[m][n], 0, 0, 0);
        }
        __syncthreads();
    }

    // epilogue: C/D layout col=lane&15, row=(lane>>4)*4+reg (m89/m91 verified)
    const int rl = (lane >> 4) * 4, cl = lane & 15;
    #pragma unroll
    for (int m = 0; m < 4; m++) {
        #pragma unroll
        for (int n = 0; n < 4; n++) {
            int gcol = j0 + wc * 64 + n * 16 + cl;
            #pragma unroll
            for (int r = 0; r < 4; r++) {
                int grow = i0 + wr * 64 + m * 16 + rl + r;
                float v = sc * acc[m][n][r];
                if (HASPREV) v += ps * bf2f(Pb[(size_t)grow * H + gcol]);
                if (grow == gcol) v += adiag;
                if (FINAL)
                    ((float*)Out)[(size_t)bz * HH + (size_t)grow * H + gcol] = v;
                else
                    ((u16*)Out)[(size_t)bz * HH + (size_t)grow * H + gcol] = f2bf(v);
            }
        }
    }
}

// ---------------- combine: U = a5 T1 + a6 T2 + a7 T3 + a8 T4   (in-place over T1)
//                  C0 = (a0-a8) I + (a1-a7) T1 + (a2-a6) T2 + (a3-a5) T3 + a4 T4 (over T2)
// NOTE: no __restrict__ — U/C0 alias T1/T2; per-thread read-before-write at same idx.
__global__ __launch_bounds__(256)
void combine_kernel(u16* t1u, u16* t2c, const u16* t3, const u16* t4,
                    float a5, float a6, float a7, float a8,
                    float cd0, float c1, float c2, float c3, float c4)
{
    const int total = BATCH * HH / 8;
    for (int idx = blockIdx.x * blockDim.x + threadIdx.x; idx < total;
         idx += gridDim.x * blockDim.x) {
        int ij8 = idx & (HH/8 - 1);
        int i = ij8 >> 5;
        int j0 = (ij8 & 31) << 3;
        u16x8 v1 = ((const u16x8*)t1u)[idx];
        u16x8 v2 = ((const u16x8*)t2c)[idx];
        u16x8 v3 = ((const u16x8*)t3)[idx];
        u16x8 v4 = ((const u16x8*)t4)[idx];
        u16x8 uo, co;
        #pragma unroll
        for (int l = 0; l < 8; l++) {
            float f1 = bf2f(v1[l]), f2 = bf2f(v2[l]), f3 = bf2f(v3[l]), f4 = bf2f(v4[l]);
            float d = (i == j0 + l) ? 1.0f : 0.0f;
            uo[l] = f2bf(a5*f1 + a6*f2 + a7*f3 + a8*f4);
            co[l] = f2bf(cd0*d + c1*f1 + c2*f2 + c3*f3 + c4*f4);
        }
        ((u16x8*)t1u)[idx] = uo;
        ((u16x8*)t2c)[idx] = co;
    }
}

// ---------------- Wsym = 0.5 (W + W^T) (fp32 + bf16 copies)
__global__ void symw_kernel(const float* __restrict__ W, float* __restrict__ Ws,
                            u16* __restrict__ Wsb)
{
    const int total = CDIM * HH;
    for (int idx = blockIdx.x * blockDim.x + threadIdx.x; idx < total;
         idx += gridDim.x * blockDim.x) {
        int c  = idx >> 16;
        int ij = idx & (HH-1);
        int i = ij >> 8, j = ij & (H-1);
        float v = 0.5f * (W[idx] + W[(c << 16) + (j << 8) + i]);
        Ws[idx] = v;
        Wsb[idx] = f2bf(v);
    }
}

// ---------------- out partials: grid (8 chunks, 128 b); feats bf16, Ws fp32
__global__ __launch_bounds__(256)
void out_partial_kernel(const u16* __restrict__ feats, const float* __restrict__ Ws,
                        float* __restrict__ partial)
{
    const int ch = blockIdx.x, b = blockIdx.y;
    const int base8 = ch * 1024;                 // ushort8 position base
    const u16x8* f8 = (const u16x8*)feats + (size_t)b * (HH/8);
    const float4* Ws4 = (const float4*)Ws;
    float acc[CDIM];
    #pragma unroll
    for (int c = 0; c < CDIM; c++) acc[c] = 0.0f;
    #pragma unroll
    for (int it = 0; it < 4; it++) {
        int p8 = base8 + it * 256 + threadIdx.x;
        u16x8 fv = f8[p8];
        float ff[8];
        #pragma unroll
        for (int l = 0; l < 8; l++) ff[l] = bf2f(fv[l]);
        #pragma unroll
        for (int c = 0; c < CDIM; c++) {
            float4 w0 = Ws4[(size_t)c * (HH/4) + p8*2];
            float4 w1 = Ws4[(size_t)c * (HH/4) + p8*2 + 1];
            acc[c] += ff[0]*w0.x + ff[1]*w0.y + ff[2]*w0.z + ff[3]*w0.w
                    + ff[4]*w1.x + ff[5]*w1.y + ff[6]*w1.z + ff[7]*w1.w;
        }
    }
    __shared__ float red[4][CDIM];
    int lane = threadIdx.x & 63, wv = threadIdx.x >> 6;
    #pragma unroll
    for (int c = 0; c < CDIM; c++) {
        float v = acc[c];
        #pragma unroll
        for (int off = 32; off >= 1; off >>= 1) v += __shfl_down(v, off, 64);
        if (lane == 0) red[wv][c] = v;
    }
    __syncthreads();
    if (threadIdx.x < CDIM)
        partial[((size_t)b * 8 + ch) * CDIM + threadIdx.x] =
            red[0][threadIdx.x] + red[1][threadIdx.x] + red[2][threadIdx.x] + red[3][threadIdx.x];
}

__global__ void out_reduce_kernel(const float* __restrict__ partial, float* __restrict__ out)
{
    int idx = blockIdx.x * blockDim.x + threadIdx.x;
    if (idx < BATCH * CDIM) {
        int b = idx / CDIM, c = idx % CDIM;
        float v = 0.0f;
        #pragma unroll
        for (int ch = 0; ch < 8; ch++) v += partial[((size_t)b * 8 + ch) * CDIM + c];
        out[idx] = v;
    }
}

// ---------------- center stage 1: partial sums over 16 batches each
__global__ __launch_bounds__(256)
void cpart_kernel(const u16* __restrict__ feats, float* __restrict__ cpart)
{
    int idx = blockIdx.x * 256 + threadIdx.x;    // ushort8 position, 0..8191
    int chunk = blockIdx.y;                      // 0..7
    const u16x8* f8 = (const u16x8*)feats;
    float s[8];
    #pragma unroll
    for (int l = 0; l < 8; l++) s[l] = 0.0f;
    for (int b = 0; b < 16; b++) {
        u16x8 v = f8[(size_t)(chunk*16 + b) * (HH/8) + idx];
        #pragma unroll
        for (int l = 0; l < 8; l++) s[l] += bf2f(v[l]);
    }
    float* dst = cpart + (size_t)chunk * HH + (size_t)idx * 8;
    *reinterpret_cast<float4*>(dst)     = make_float4(s[0], s[1], s[2], s[3]);
    *reinterpret_cast<float4*>(dst + 4) = make_float4(s[4], s[5], s[6], s[7]);
}

// ---------------- center stage 2: sum 8 chunks, /128, write bf16
__global__ __launch_bounds__(256)
void cfinal_kernel(const float* __restrict__ cpart, u16* __restrict__ centerb)
{
    int idx = blockIdx.x * 256 + threadIdx.x;    // 0..8191
    float s[8];
    #pragma unroll
    for (int l = 0; l < 8; l++) s[l] = 0.0f;
    #pragma unroll
    for (int ch = 0; ch < 8; ch++) {
        const float* src = cpart + (size_t)ch * HH + (size_t)idx * 8;
        float4 p0 = *reinterpret_cast<const float4*>(src);
        float4 p1 = *reinterpret_cast<const float4*>(src + 4);
        s[0]+=p0.x; s[1]+=p0.y; s[2]+=p0.z; s[3]+=p0.w;
        s[4]+=p1.x; s[5]+=p1.y; s[6]+=p1.z; s[7]+=p1.w;
    }
    u16x8 o;
    #pragma unroll
    for (int l = 0; l < 8; l++) o[l] = f2bf(s[l] * (1.0f / BATCH));
    ((u16x8*)centerb)[idx] = o;
}

// ---------------- g partial: grid (CDIM, 8); 32 rows per block
__global__ __launch_bounds__(256)
void g_kernel(const float* __restrict__ P, float* __restrict__ gpart)
{
    int c = blockIdx.x, r0 = blockIdx.y * 32;
    const float* Pc = P + (size_t)c * HH;
    float acc = 0.0f;
    for (int idx = threadIdx.x; idx < 32 * H; idx += 256) {
        int i = r0 + (idx >> 8), j = idx & (H-1);
        acc += Pc[i * H + j] * Pc[j * H + i];
    }
    __shared__ float red[4];
    int lane = threadIdx.x & 63, wv = threadIdx.x >> 6;
    #pragma unroll
    for (int off = 32; off >= 1; off >>= 1) acc += __shfl_down(acc, off, 64);
    if (lane == 0) red[wv] = acc;
    __syncthreads();
    if (threadIdx.x == 0)
        gpart[c * 8 + blockIdx.y] = red[0] + red[1] + red[2] + red[3];
}

__global__ void gmean_kernel(const float* __restrict__ gpart, float* __restrict__ out)
{
    if (threadIdx.x == 0) {
        float s = 0.0f;
        for (int i = 0; i < CDIM * 8; i++) s += gpart[i];
        out[BATCH*CDIM] = s * (1.0f / CDIM);
    }
}

extern "C" void kernel_launch(void* const* d_in, const int* in_sizes, int n_in,
                              void* d_out, int out_size, void* d_ws, size_t ws_size,
                              hipStream_t stream)
{
    const float* X = (const float*)d_in[0];   // [128,256,256]
    const float* W = (const float*)d_in[1];   // [10,256,256]
    float* out = (float*)d_out;               // 1281 floats

    char* wp = (char*)d_ws;
    u16* tb  = (u16*)wp;  wp += (size_t)BATCH * HH * 2;   // T1 -> U (in-place)
    u16* T2  = (u16*)wp;  wp += (size_t)BATCH * HH * 2;   // T2 -> C0 (in-place)
    u16* T3  = (u16*)wp;  wp += (size_t)BATCH * HH * 2;   // T3 -> feats (bf16)
    u16* T4  = (u16*)wp;  wp += (size_t)BATCH * HH * 2;
    float* Wsym   = (float*)wp;  wp += (size_t)CDIM * HH * 4;
    u16*   Wsb    = (u16*)wp;    wp += (size_t)CDIM * HH * 2;
    u16*   centerb= (u16*)wp;    wp += (size_t)HH * 2;
    float* P      = (float*)wp;  wp += (size_t)CDIM * HH * 4;
    float* cpart  = (float*)wp;  wp += (size_t)8 * HH * 4;
    float* partial= (float*)wp;  wp += (size_t)BATCH * 8 * CDIM * 4;
    float* gpart  = (float*)wp;

    // Chebyshev coefficients of log(x) on [lo, hi] (closed form)
    const double lo = 0.98, hi = 5.80;
    const double cc = 0.5 * (hi + lo), hh = 0.5 * (hi - lo);
    const double alpha = hh / cc;
    const double beta = (sqrt(1.0 - alpha*alpha) - 1.0) / alpha;
    double a[NCHEB + 1];
    a[0] = log(cc) - log(1.0 + beta*beta);
    double bp = 1.0;
    for (int k = 1; k <= NCHEB; k++) { bp *= beta; a[k] = -2.0 * bp / k; }

    prep_kernel<<<1024, 256, 0, stream>>>((const float4*)X, (ushort4*)tb,
                                          (float)cc, (float)(1.0 / hh));
    symw_kernel<<<64, 256, 0, stream>>>(W, Wsym, Wsb);

    dim3 mmgrid(2, 2, BATCH);
    // T2 = 2 t@t - I
    mm_bf16_kernel<0,0><<<mmgrid, 256, 0, stream>>>(tb, tb, nullptr, T2, 1, 2.0f, 0.0f, -1.0f);
    // T3 = 2 t@T2 - t
    mm_bf16_kernel<0,1><<<mmgrid, 256, 0, stream>>>(tb, T2, tb, T3, 1, 2.0f, -1.0f, 0.0f);
    // T4 = 2 t@T3 - T2
    mm_bf16_kernel<0,1><<<mmgrid, 256, 0, stream>>>(tb, T3, T2, T4, 1, 2.0f, -1.0f, 0.0f);
    // U (over tb), C0 (over T2)
    combine_kernel<<<2048, 256, 0, stream>>>(
        tb, T2, T3, T4,
        (float)a[5], (float)a[6], (float)a[7], (float)a[8],
        (float)(a[0] - a[8]), (float)(a[1] - a[7]), (float)(a[2] - a[6]),
        (float)(a[3] - a[5]), (float)a[4]);
    // feats = 2 T4@U + C0  (bf16, into T3 buffer)
    mm_bf16_kernel<0,1><<<mmgrid, 256, 0, stream>>>(T4, tb, T2, T3, 1, 2.0f, 1.0f, 0.0f);
    u16* feats = T3;

    out_partial_kernel<<<dim3(8, BATCH), 256, 0, stream>>>(feats, Wsym, partial);
    out_reduce_kernel<<<5, 256, 0, stream>>>(partial, out);

    cpart_kernel<<<dim3(32, 8), 256, 0, stream>>>(feats, cpart);
    cfinal_kernel<<<32, 256, 0, stream>>>(cpart, centerb);

    // P[c] = Wsym_bf16[c] @ center  (fp32 out)
    mm_bf16_kernel<1,0><<<dim3(2, 2, CDIM), 256, 0, stream>>>(
        Wsb, centerb, nullptr, P, 0, 1.0f, 0.0f, 0.0f);
    g_kernel<<<dim3(CDIM, 8), 256, 0, stream>>>(P, gpart);
    gmean_kernel<<<1, 64, 0, stream>>>(gpart, out);
}